// Round 6
// baseline (97.492 us; speedup 1.0000x reference)
//
#include <hip/hip_runtime.h>
#include <math.h>

// ---- problem constants ----
#define NRAD 48
#define NANG 72
#define HV   3456            // valid hashes = NRAD*NANG
#define HVW  864             // HV/4 (u32 words of packed u8 counters)
#define MAXP 64
#define MAXV 3000
#define BLK  256
#define CHT  64              // tiles per scan chunk
#define TILE 4096
#define SUBT 1024            // per-wave sub-tile in fast scatter (TILE/4)
#define NCH  16              // chunks per sub-tile (SUBT/64)

// output layout (floats)
#define OFF_C   (MAXV*MAXP*5)          // 960000
#define OFF_N   (OFF_C + MAXV*3)       // 969000
#define OFF_X   (OFF_N + MAXV)         // 972000

#define PI_F 3.14159265358979323846f   // rounds to 0x40490FDB

// np.linspace(-pi, pi, 73) in f64 (y = i*step + start, endpoint forced), cast f32.
__device__ __forceinline__ float angle_edge(int j) {
  const double PI = 3.14159265358979311599796346854;
  const double step = (PI - (-PI)) / 72.0;
  if (j == 72) return (float)PI;
  return (float)(-PI + (double)j * step);
}

// bin per reference semantics; fast f32 atan estimate decides unless within
// GUARD of an edge, then exact (float)atan2(f64) fallback (bit-identical).
__device__ __forceinline__ int point_bin(float x, float y, float z,
                                         const float* __restrict__ eang) {
  float r = __fsqrt_rn(__fadd_rn(__fmul_rn(x, x), __fmul_rn(y, y)));
  if (!(z >= -3.0f && z < 5.0f && r >= 2.0f && r < 50.0f)) return HV;
  int ri = (int)ceilf(r) - 3;                 // exact: edges are ints 2..50
  ri = max(0, min(NRAD - 1, ri));
  float ax = fabsf(x), ay = fabsf(y);
  float u = fminf(ax, ay), U = fmaxf(ax, ay);
  bool big = u > 0.41421356f * U;             // tan(pi/8); either branch valid at tie
  float num = big ? (U - u) : u;
  float den = big ? (U + u) : U;
  float v = num / den;                        // in [0, 0.41422]
  float s = v * v;
  float a = 0.05882353f;
  a = a * s - 0.06666667f;
  a = a * s + 0.07692308f;
  a = a * s - 0.09090909f;
  a = a * s + 0.11111111f;
  a = a * s - 0.14285714f;
  a = a * s + 0.2f;
  a = a * s - 0.33333333f;
  a = a * s + 1.0f;
  float pp = v * a;                           // atan(v)
  float th1 = big ? (0.78539816f - pp) : pp;
  if (ay > ax) th1 = 1.57079633f - th1;
  if (x < 0.0f) th1 = PI_F - th1;
  float that = copysignf(th1, y);
  int g = (int)floorf((that + PI_F) * 11.459155902616465f);
  g = max(0, min(NANG - 1, g));
  while (g > 0 && !(eang[g] < that)) g--;
  while (g < NANG - 1 && eang[g + 1] < that) g++;
  float d0 = that - eang[g];
  float d1 = eang[g + 1] - that;
  const float GUARD = 2e-5f;
  if (d0 > GUARD && d1 > GUARD) return ri * NANG + g;
  // exact path (rare)
  float th = (float)atan2((double)y, (double)x);
  if (!(th >= eang[0] && th < eang[72])) return HV;
  int gg = g;
  while (gg > 0 && !(eang[gg] < th)) gg--;
  while (gg < NANG - 1 && eang[gg + 1] < th) gg++;
  return ri * NANG + max(0, min(NANG - 1, gg));
}

// ---- pass 1: zero d_out + flags + per-tile saturated u8 histogram + bin cache ----
__global__ __launch_bounds__(BLK) void k_hist(
    const float* __restrict__ pts, int N, int tile, int n4, int tailN,
    unsigned char* __restrict__ hist, unsigned short* __restrict__ bins,
    float4* __restrict__ out4, int* __restrict__ flags) {
  __shared__ int lh[HV];
  __shared__ float eang[73];
  int t = blockIdx.x, tid = threadIdx.x;
  for (int j = t * BLK + tid; j < n4; j += gridDim.x * BLK)
    out4[j] = make_float4(0.f, 0.f, 0.f, 0.f);
  if (t == 0 && tid < tailN) ((float*)out4)[(size_t)n4 * 4 + tid] = 0.f;
  if (t == 0 && tid >= 64 && tid < 96) flags[tid - 64] = 0;   // reset chain flags
  for (int i = tid; i < HV; i += BLK) lh[i] = 0;
  if (tid < 73) eang[tid] = angle_edge(tid);
  __syncthreads();
  int base = t * tile;
  int end  = min(base + tile, N);
  int endq = base + (((end - base) >> 2) << 2);
  const float4* p4 = (const float4*)pts;
  for (int i0 = base + (tid << 2); i0 < endq; i0 += (BLK << 2)) {
    size_t q = (size_t)(i0 >> 2) * 5;
    float4 v0 = p4[q], v1 = p4[q + 1], v2 = p4[q + 2], v3 = p4[q + 3], v4 = p4[q + 4];
    int b0 = point_bin(v0.x, v0.y, v0.z, eang);
    int b1 = point_bin(v1.y, v1.z, v1.w, eang);
    int b2 = point_bin(v2.z, v2.w, v3.x, eang);
    int b3 = point_bin(v3.w, v4.x, v4.y, eang);
    *(ushort4*)(bins + i0) = make_ushort4((unsigned short)b0, (unsigned short)b1,
                                          (unsigned short)b2, (unsigned short)b3);
    if (b0 < HV) atomicAdd(&lh[b0], 1);
    if (b1 < HV) atomicAdd(&lh[b1], 1);
    if (b2 < HV) atomicAdd(&lh[b2], 1);
    if (b3 < HV) atomicAdd(&lh[b3], 1);
  }
  for (int i = endq + tid; i < end; i += BLK) {   // <=3 tail points
    size_t p = (size_t)i * 5;
    int b = point_bin(pts[p], pts[p + 1], pts[p + 2], eang);
    bins[i] = (unsigned short)b;
    if (b < HV) atomicAdd(&lh[b], 1);
  }
  __syncthreads();
  unsigned char* ht = hist + (size_t)t * HV;
  for (int i = tid; i < HV; i += BLK) ht[i] = (unsigned char)min(lh[i], 64);
}

// ---- pass 2 (fused): flat decoupled saturated scan + slots/coords/num/centers ----
// Blocks 0..NC-1: per-chunk sums -> publish (fence+flag) -> poll all flags ->
// local satsum of earlier chunks = global base -> write per-tile exclusive
// offsets in place. Block NC: poll all flags -> per-bin totals -> slot scan +
// coords/num_points/centers. 17 blocks << 256 CUs => trivially co-resident;
// flags go through device-scope atomics (G16).
__global__ __launch_bounds__(1024) void k_scan2(
    unsigned int* __restrict__ hist32, int NT, int NC,
    unsigned int* __restrict__ part32, int* flags,
    int* __restrict__ soh, float* __restrict__ out) {
  int c = blockIdx.x;
  int tid = threadIdx.x;
  if (c < NC) {
    int t0 = c * CHT, t1 = min(t0 + CHT, NT);
    if (tid < HVW) {
      int s0 = 0, s1 = 0, s2 = 0, s3 = 0;
      for (int t = t0; t < t1; ++t) {
        unsigned int v = hist32[(size_t)t * HVW + tid];
        s0 = min(s0 + (int)(v & 255u), 64);
        s1 = min(s1 + (int)((v >> 8) & 255u), 64);
        s2 = min(s2 + (int)((v >> 16) & 255u), 64);
        s3 = min(s3 + (int)(v >> 24), 64);
      }
      part32[(size_t)c * HVW + tid] = (unsigned)s0 | ((unsigned)s1 << 8) |
                                      ((unsigned)s2 << 16) | ((unsigned)s3 << 24);
    }
    __threadfence();
    __syncthreads();
    if (tid == 0) atomicExch(&flags[c], 1);
    if (tid < NC) { while (atomicAdd(&flags[tid], 0) == 0) {} }
    __threadfence();
    __syncthreads();
    if (tid < HVW) {
      int r0 = 0, r1 = 0, r2 = 0, r3 = 0;
      for (int cc = 0; cc < c; ++cc) {
        unsigned int v = part32[(size_t)cc * HVW + tid];
        r0 = min(r0 + (int)(v & 255u), 64);
        r1 = min(r1 + (int)((v >> 8) & 255u), 64);
        r2 = min(r2 + (int)((v >> 16) & 255u), 64);
        r3 = min(r3 + (int)(v >> 24), 64);
      }
      for (int t = t0; t < t1; ++t) {
        size_t o = (size_t)t * HVW + tid;
        unsigned int v = hist32[o];
        hist32[o] = (unsigned)r0 | ((unsigned)r1 << 8) |
                    ((unsigned)r2 << 16) | ((unsigned)r3 << 24);
        r0 = min(r0 + (int)(v & 255u), 64);
        r1 = min(r1 + (int)((v >> 8) & 255u), 64);
        r2 = min(r2 + (int)((v >> 16) & 255u), 64);
        r3 = min(r3 + (int)(v >> 24), 64);
      }
    }
  } else {
    // finisher: slot assignment + coords/num_points/centers
    __shared__ int ssum[1024];
    if (tid < NC) { while (atomicAdd(&flags[tid], 0) == 0) {} }
    __threadfence();
    __syncthreads();
    int c0 = 0, c1 = 0, c2 = 0, c3 = 0;
    if (tid < HVW) {
      for (int cc = 0; cc < NC; ++cc) {
        unsigned int v = part32[(size_t)cc * HVW + tid];
        c0 = min(c0 + (int)(v & 255u), 64);
        c1 = min(c1 + (int)((v >> 8) & 255u), 64);
        c2 = min(c2 + (int)((v >> 16) & 255u), 64);
        c3 = min(c3 + (int)(v >> 24), 64);
      }
    }
    int occ = (c0 > 0) + (c1 > 0) + (c2 > 0) + (c3 > 0);
    ssum[tid] = occ;
    __syncthreads();
    for (int off = 1; off < 1024; off <<= 1) {
      int v = (tid >= off) ? ssum[tid - off] : 0;
      __syncthreads();
      ssum[tid] += v;
      __syncthreads();
    }
    int base = ssum[tid] - occ;               // exclusive slot base (bin order)
    if (tid < HVW) {
      int cs[4] = {c0, c1, c2, c3};
#pragma unroll
      for (int k = 0; k < 4; ++k) {
        int h = tid * 4 + k;
        int cnt = cs[k];
        int s = -1;
        if (cnt > 0) {
          if (base < MAXV) s = base;
          base++;
        }
        soh[h] = s;
        if (s >= 0) {
          int ri = h / NANG, ti = h % NANG;
          out[OFF_C + s * 3 + 0] = (float)ri;
          out[OFF_C + s * 3 + 1] = (float)ti;
          out[OFF_C + s * 3 + 2] = 0.0f;
          out[OFF_N + s] = (float)cnt;        // already saturated at 64
          float rc = 2.5f + (float)ri;
          float e0 = angle_edge(ti), e1 = angle_edge(ti + 1);
          float tc = 0.5f * (e0 + e1);
          out[OFF_X + s * 2 + 0] = rc * cosf(tc);   // ~5e-5 abs err << threshold
          out[OFF_X + s * 2 + 1] = rc * sinf(tc);
        }
      }
    }
  }
}

// ---- pass 3 (fast, tile==4096): ballot-rank scatter with dead-bin pruning ----
__global__ __launch_bounds__(BLK) void k_scatter_fast(
    const float* __restrict__ pts, int N,
    const unsigned char* __restrict__ hist, const unsigned short* __restrict__ bins,
    const int* __restrict__ soh, float* __restrict__ out) {
  __shared__ unsigned int whd[4 * HV / 2];          // 4 x HV u16 = 27648 B
  unsigned short (*wh)[HV] = (unsigned short (*)[HV])whd;
  int t = blockIdx.x;
  int tid = threadIdx.x;
  int lane = tid & 63, wv = tid >> 6;
  for (int i = tid; i < 4 * HV / 2; i += BLK) whd[i] = 0u;
  __syncthreads();
  int base = t * TILE;
  int end  = min(base + TILE, N);
  int sb = base + wv * SUBT;
  int se = min(sb + SUBT, end);
  const unsigned char* ht = hist + (size_t)t * HV;  // saturated tile-start offsets
  unsigned short lb[NCH], lr[NCH];
  const unsigned long long lmask = (1ULL << lane) - 1ULL;
#pragma unroll
  for (int c = 0; c < NCH; ++c) {
    int i = sb + c * 64 + lane;
    int b = 4095;                                   // sentinel (> any real bin)
    if (i < se) {
      int bi = bins[i];
      if (bi < HV && ht[bi] < 64) b = bi;           // prune dead bins
    }
    lb[c] = (unsigned short)b;
    lr[c] = 0;
    if (__ballot(b != 4095) == 0ULL) continue;      // whole chunk dead
    unsigned long long m = ~0ULL;
#pragma unroll
    for (int k = 0; k < 12; ++k) {
      unsigned long long bal = __ballot((b >> k) & 1);
      m &= ((b >> k) & 1) ? bal : ~bal;
    }
    int rho = __popcll(m & lmask);                  // same-bin lanes before me
    int kap = __popcll(m);                          // same-bin lanes in chunk
    int cv = 0;
    if (b != 4095) {
      cv = wh[wv][b];                               // read before leader write
      if (rho == 0) wh[wv][b] = (unsigned short)(cv + kap);
    }
    lr[c] = (unsigned short)(cv + rho);
  }
  __syncthreads();
  for (int j = tid; j < HV; j += BLK) {
    int a0 = wh[0][j], a1 = wh[1][j], a2 = wh[2][j];
    wh[0][j] = 0;
    wh[1][j] = (unsigned short)a0;
    wh[2][j] = (unsigned short)(a0 + a1);
    wh[3][j] = (unsigned short)(a0 + a1 + a2);
  }
  __syncthreads();
#pragma unroll
  for (int c = 0; c < NCH; ++c) {
    int b = lb[c];
    if (b == 4095) continue;
    int rank = (int)ht[b] + (int)wh[wv][b] + (int)lr[c];
    if (rank < MAXP) {
      int s = soh[b];
      if (s >= 0) {
        int i = sb + c * 64 + lane;
        size_t dst = (size_t)(s * MAXP + rank) * 5;
        size_t src = (size_t)i * 5;
        out[dst + 0] = pts[src + 0];
        out[dst + 1] = pts[src + 1];
        out[dst + 2] = pts[src + 2];
        out[dst + 3] = pts[src + 3];
        out[dst + 4] = pts[src + 4];
      }
    }
  }
}

// ---- pass 3 (generic fallback, any tile) ----
__global__ void k_scatter_gen(const float* __restrict__ pts, int N, int tile,
                              const unsigned char* __restrict__ hist,
                              const unsigned short* __restrict__ bins,
                              const int* __restrict__ soh,
                              float* __restrict__ out) {
  __shared__ int cur[HV + 1];
  int t = blockIdx.x;
  int tid = threadIdx.x;
  const unsigned char* ht = hist + (size_t)t * HV;
  for (int i = tid; i < HV + 1; i += BLK) cur[i] = (i < HV) ? (int)ht[i] : 0;
  __syncthreads();
  int base = t * tile;
  int end  = min(base + tile, N);
  int lane = tid & 63, wv = tid >> 6;
  for (int g = base; g < base + tile; g += BLK) {
    int i = g + tid;
    bool act = (i < end);
    int b = act ? (int)bins[i] : 0x10000;
    int rho = 0, kap = 0;
    for (int j = 0; j < 64; ++j) {
      int bj = __shfl(b, j, 64);
      if (bj == b) { kap++; if (j < lane) rho++; }
    }
    int rank = 0x7FFFFFFF;
    for (int w = 0; w < 4; ++w) {
      if (wv == w && act) {
        int bs = cur[b];
        rank = bs + rho;
        if (rho == 0) cur[b] = bs + kap;
      }
      __syncthreads();
    }
    if (act && rank < MAXP && b < HV) {
      int s = soh[b];
      if (s >= 0) {
        size_t dst = (size_t)(s * MAXP + rank) * 5;
        size_t src = (size_t)i * 5;
        out[dst + 0] = pts[src + 0];
        out[dst + 1] = pts[src + 1];
        out[dst + 2] = pts[src + 2];
        out[dst + 3] = pts[src + 3];
        out[dst + 4] = pts[src + 4];
      }
    }
  }
}

extern "C" void kernel_launch(void* const* d_in, const int* in_sizes, int n_in,
                              void* d_out, int out_size, void* d_ws, size_t ws_size,
                              hipStream_t stream) {
  const float* pts = (const float*)d_in[0];
  int N = in_sizes[0] / 5;
  float* out = (float*)d_out;

  auto align = [](size_t x) { return (x + 255) & ~(size_t)255; };
  int tile = TILE, NT = 1, NC = 1;
  size_t o_hist = 0, o_part = 0, o_soh = 0, o_flag = 0, o_bins = 0;
  for (;;) {
    NT = (N + tile - 1) / tile;
    NC = (NT + CHT - 1) / CHT;
    o_hist = 0;
    o_part = align(o_hist + (size_t)NT * HV);
    o_soh  = align(o_part + (size_t)NC * HV);
    o_flag = align(o_soh + (size_t)HV * 4);
    o_bins = align(o_flag + 256);
    size_t need = o_bins + (size_t)N * 2;
    if (need <= ws_size || tile >= (1 << 22)) break;
    tile <<= 1;
  }

  char* w = (char*)d_ws;
  unsigned char* hist = (unsigned char*)(w + o_hist);
  unsigned int*  hist32 = (unsigned int*)hist;
  unsigned int*  part32 = (unsigned int*)(w + o_part);
  int* soh   = (int*)(w + o_soh);
  int* flags = (int*)(w + o_flag);
  unsigned short* bins = (unsigned short*)(w + o_bins);

  int n4 = out_size / 4;
  int tailN = out_size - n4 * 4;

  k_hist<<<NT, BLK, 0, stream>>>(pts, N, tile, n4, tailN, hist, bins,
                                 (float4*)out, flags);
  k_scan2<<<NC + 1, 1024, 0, stream>>>(hist32, NT, NC, part32, flags, soh, out);
  if (tile == TILE) {
    k_scatter_fast<<<NT, BLK, 0, stream>>>(pts, N, hist, bins, soh, out);
  } else {
    k_scatter_gen<<<NT, BLK, 0, stream>>>(pts, N, tile, hist, bins, soh, out);
  }
}

// Round 7
// 93.465 us; speedup vs baseline: 1.0431x; 1.0431x over previous
//
#include <hip/hip_runtime.h>
#include <math.h>

// ---- problem constants ----
#define NRAD 48
#define NANG 72
#define HV   3456            // valid hashes = NRAD*NANG
#define HVW  864             // HV/4 (u32 words of packed u8 counters)
#define MAXP 64
#define MAXV 3000
#define BLK  256
#define CHT  64              // tiles per scan chunk
#define TILE 4096
#define SUBT 1024            // per-wave sub-tile in fast scatter (TILE/4)
#define NCH  16              // chunks per sub-tile (SUBT/64)

// output layout (floats)
#define OFF_C   (MAXV*MAXP*5)          // 960000
#define OFF_N   (OFF_C + MAXV*3)       // 969000
#define OFF_X   (OFF_N + MAXV)         // 972000

#define PI_F 3.14159265358979323846f   // rounds to 0x40490FDB

// np.linspace(-pi, pi, 73) in f64 (y = i*step + start, endpoint forced), cast f32.
__device__ __forceinline__ float angle_edge(int j) {
  const double PI = 3.14159265358979311599796346854;
  const double step = (PI - (-PI)) / 72.0;
  if (j == 72) return (float)PI;
  return (float)(-PI + (double)j * step);
}

// Angular bin via cross-product sign tests against precomputed edge directions.
// cross_j = cos(phi_j)*y - sin(phi_j)*x = r*sin(theta - phi_j): decides
// "theta > edge_j" exactly outside a +/-GA guard band; inside the band we fall
// back to the bit-exact (float)atan2(f64) reference path. Guard 2e-6*r covers
// cross rounding (~4e-7*r) and the reference's own theta f32 rounding (1.2e-7).
__device__ __forceinline__ int point_bin(float x, float y, float z,
                                         const float* __restrict__ eang,
                                         const float* __restrict__ ec,
                                         const float* __restrict__ es) {
  float r = __fsqrt_rn(__fadd_rn(__fmul_rn(x, x), __fmul_rn(y, y)));
  if (!(z >= -3.0f && z < 5.0f && r >= 2.0f && r < 50.0f)) return HV;
  int ri = (int)ceilf(r) - 3;                 // exact: edges are ints 2..50
  ri = max(0, min(NRAD - 1, ri));
  // cheap guess (err ~3e-4 rad): octant reduce, v_rcp divide, 3-term poly
  float ax = fabsf(x), ay = fabsf(y);
  float u = fminf(ax, ay), U = fmaxf(ax, ay);
  bool big = u > 0.41421356f * U;
  float num = big ? (U - u) : u;
  float den = big ? (U + u) : U;
  float v = num * __builtin_amdgcn_rcpf(den);
  float s2 = v * v;
  float pp = v * (1.0f + s2 * (-0.33333333f + s2 * (0.2f - s2 * 0.14285714f)));
  float th1 = big ? (0.78539816f - pp) : pp;
  if (ay > ax) th1 = 1.57079633f - th1;
  if (x < 0.0f) th1 = PI_F - th1;
  float that = copysignf(th1, y);
  int g = (int)floorf((that + PI_F) * 11.459155902616465f);
  g = max(0, min(NANG - 1, g));
  float GA = 2e-6f * r;
  bool unc = false;
  for (;;) {                                   // ensure theta > edge_g (certainly)
    float d = __fmaf_rn(ec[g], y, -__fmul_rn(es[g], x));
    if (d > GA) break;
    if (d > -GA || g == 0) { unc = true; break; }
    --g;
  }
  if (!unc) {
    while (g < NANG - 1) {                     // advance while theta > edge_{g+1}
      float d = __fmaf_rn(ec[g + 1], y, -__fmul_rn(es[g + 1], x));
      if (d < -GA) break;
      if (d <= GA) { unc = true; break; }
      ++g;
    }
    if (!unc && g == NANG - 1) {               // upper validity: theta < eang[72]
      float d = __fmaf_rn(ec[72], y, -__fmul_rn(es[72], x));
      if (d >= -GA) unc = true;
    }
  }
  if (!unc) return ri * NANG + g;
  // exact fallback (rare, ~5e-5 of points): bit-identical to reference
  float th = (float)atan2((double)y, (double)x);
  if (!(th >= eang[0] && th < eang[72])) return HV;
  int gg = g;
  while (gg > 0 && !(eang[gg] < th)) gg--;
  while (gg < NANG - 1 && eang[gg + 1] < th) gg++;
  return ri * NANG + max(0, min(NANG - 1, gg));
}

// ---- pass 1: zero d_out + per-tile saturated u8 histogram + bin cache ----
__global__ __launch_bounds__(BLK) void k_hist(
    const float* __restrict__ pts, int N, int tile, int n4, int tailN,
    unsigned char* __restrict__ hist, unsigned short* __restrict__ bins,
    float4* __restrict__ out4) {
  __shared__ int lh[HV];
  __shared__ float eang[73], ec[73], es[73];
  int t = blockIdx.x, tid = threadIdx.x;
  for (int j = t * BLK + tid; j < n4; j += gridDim.x * BLK)
    out4[j] = make_float4(0.f, 0.f, 0.f, 0.f);
  if (t == 0 && tid < tailN) ((float*)out4)[(size_t)n4 * 4 + tid] = 0.f;
  for (int i = tid; i < HV; i += BLK) lh[i] = 0;
  if (tid < 73) {
    float e = angle_edge(tid);
    eang[tid] = e;
    ec[tid] = (float)cos((double)e);
    es[tid] = (float)sin((double)e);
  }
  __syncthreads();
  int base = t * tile;
  int end  = min(base + tile, N);
  int endq = base + (((end - base) >> 2) << 2);
  const float4* p4 = (const float4*)pts;
  for (int i0 = base + (tid << 2); i0 < endq; i0 += (BLK << 2)) {
    size_t q = (size_t)(i0 >> 2) * 5;
    float4 v0 = p4[q], v1 = p4[q + 1], v2 = p4[q + 2], v3 = p4[q + 3], v4 = p4[q + 4];
    int b0 = point_bin(v0.x, v0.y, v0.z, eang, ec, es);
    int b1 = point_bin(v1.y, v1.z, v1.w, eang, ec, es);
    int b2 = point_bin(v2.z, v2.w, v3.x, eang, ec, es);
    int b3 = point_bin(v3.w, v4.x, v4.y, eang, ec, es);
    *(ushort4*)(bins + i0) = make_ushort4((unsigned short)b0, (unsigned short)b1,
                                          (unsigned short)b2, (unsigned short)b3);
    if (b0 < HV) atomicAdd(&lh[b0], 1);
    if (b1 < HV) atomicAdd(&lh[b1], 1);
    if (b2 < HV) atomicAdd(&lh[b2], 1);
    if (b3 < HV) atomicAdd(&lh[b3], 1);
  }
  for (int i = endq + tid; i < end; i += BLK) {   // <=3 tail points
    size_t p = (size_t)i * 5;
    int b = point_bin(pts[p], pts[p + 1], pts[p + 2], eang, ec, es);
    bins[i] = (unsigned short)b;
    if (b < HV) atomicAdd(&lh[b], 1);
  }
  __syncthreads();
  unsigned char* ht = hist + (size_t)t * HV;
  for (int i = tid; i < HV; i += BLK) ht[i] = (unsigned char)min(lh[i], 64);
}

// ---- pass 2a: per-chunk saturated sums (u32-packed u8 lanes) ----
__global__ void k_scan_a(const unsigned int* __restrict__ hist32, int NT,
                         unsigned int* __restrict__ part32) {
  int w = blockIdx.x * BLK + threadIdx.x;     // word 0..HVW-1 (4 bins per word)
  int c = blockIdx.y;
  if (w >= HVW) return;
  int t0 = c * CHT, t1 = min(t0 + CHT, NT);
  int s0 = 0, s1 = 0, s2 = 0, s3 = 0;
  for (int t = t0; t < t1; ++t) {
    unsigned int v = hist32[(size_t)t * HVW + w];
    s0 = min(s0 + (int)(v & 255u), 64);
    s1 = min(s1 + (int)((v >> 8) & 255u), 64);
    s2 = min(s2 + (int)((v >> 16) & 255u), 64);
    s3 = min(s3 + (int)(v >> 24), 64);
  }
  part32[(size_t)c * HVW + w] = (unsigned)s0 | ((unsigned)s1 << 8) |
                                ((unsigned)s2 << 16) | ((unsigned)s3 << 24);
}

// ---- pass 2b fused: chunk-exclusive scan + slot assignment + coords/num/centers ----
__global__ __launch_bounds__(1024) void k_bsc(unsigned int* __restrict__ part32, int NC,
                                              int* __restrict__ soh,
                                              float* __restrict__ out) {
  __shared__ float eang[73];
  __shared__ int ssum[1024];
  int tid = threadIdx.x;
  if (tid < 73) eang[tid] = angle_edge(tid);
  int r0 = 0, r1 = 0, r2 = 0, r3 = 0;
  for (int cb = 0; cb < NC; cb += 16) {
    unsigned int vv[16];
#pragma unroll
    for (int k = 0; k < 16; ++k) {
      int c = cb + k;
      vv[k] = (tid < HVW && c < NC) ? part32[(size_t)c * HVW + tid] : 0u;
    }
#pragma unroll
    for (int k = 0; k < 16; ++k) {
      int c = cb + k;
      if (tid < HVW && c < NC)
        part32[(size_t)c * HVW + tid] = (unsigned)r0 | ((unsigned)r1 << 8) |
                                        ((unsigned)r2 << 16) | ((unsigned)r3 << 24);
      r0 = min(r0 + (int)(vv[k] & 255u), 64);
      r1 = min(r1 + (int)((vv[k] >> 8) & 255u), 64);
      r2 = min(r2 + (int)((vv[k] >> 16) & 255u), 64);
      r3 = min(r3 + (int)(vv[k] >> 24), 64);
    }
  }
  int c0 = r0, c1 = r1, c2 = r2, c3 = r3;
  int occ = (c0 > 0) + (c1 > 0) + (c2 > 0) + (c3 > 0);
  if (tid >= HVW) occ = 0;
  ssum[tid] = occ;
  __syncthreads();
  for (int off = 1; off < 1024; off <<= 1) {
    int v = (tid >= off) ? ssum[tid - off] : 0;
    __syncthreads();
    ssum[tid] += v;
    __syncthreads();
  }
  int base = ssum[tid] - occ;                 // exclusive slot base (bin order)
  if (tid < HVW) {
    int cs[4] = {c0, c1, c2, c3};
#pragma unroll
    for (int k = 0; k < 4; ++k) {
      int h = tid * 4 + k;
      int cnt = cs[k];
      int s = -1;
      if (cnt > 0) {
        if (base < MAXV) s = base;
        base++;
      }
      soh[h] = s;
      if (s >= 0) {
        int ri = h / NANG, ti = h % NANG;
        out[OFF_C + s * 3 + 0] = (float)ri;
        out[OFF_C + s * 3 + 1] = (float)ti;
        out[OFF_C + s * 3 + 2] = 0.0f;
        out[OFF_N + s] = (float)cnt;          // already saturated at 64
        float rc = 2.5f + (float)ri;
        float tc = 0.5f * (eang[ti] + eang[ti + 1]);
        out[OFF_X + s * 2 + 0] = rc * cosf(tc);   // ~5e-5 abs err << threshold
        out[OFF_X + s * 2 + 1] = rc * sinf(tc);
      }
    }
  }
}

// ---- pass 2c: in-place exclusive tile-start scan within each chunk (saturated) ----
__global__ void k_scan_c(unsigned int* __restrict__ hist32, int NT,
                         const unsigned int* __restrict__ part32) {
  int w = blockIdx.x * BLK + threadIdx.x;
  int c = blockIdx.y;
  if (w >= HVW) return;
  int t0 = c * CHT, t1 = min(t0 + CHT, NT);
  unsigned int pv = part32[(size_t)c * HVW + w];
  int r0 = pv & 255u, r1 = (pv >> 8) & 255u, r2 = (pv >> 16) & 255u, r3 = pv >> 24;
  for (int t = t0; t < t1; ++t) {
    size_t o = (size_t)t * HVW + w;
    unsigned int v = hist32[o];
    hist32[o] = (unsigned)r0 | ((unsigned)r1 << 8) |
                ((unsigned)r2 << 16) | ((unsigned)r3 << 24);
    r0 = min(r0 + (int)(v & 255u), 64);
    r1 = min(r1 + (int)((v >> 8) & 255u), 64);
    r2 = min(r2 + (int)((v >> 16) & 255u), 64);
    r3 = min(r3 + (int)(v >> 24), 64);
  }
}

// ---- pass 3 (fast, tile==4096): ballot-rank scatter with dead-bin pruning ----
__global__ __launch_bounds__(BLK) void k_scatter_fast(
    const float* __restrict__ pts, int N,
    const unsigned char* __restrict__ hist, const unsigned short* __restrict__ bins,
    const int* __restrict__ soh, float* __restrict__ out) {
  __shared__ unsigned int whd[4 * HV / 2];          // 4 x HV u16 = 27648 B
  unsigned short (*wh)[HV] = (unsigned short (*)[HV])whd;
  int t = blockIdx.x;
  int tid = threadIdx.x;
  int lane = tid & 63, wv = tid >> 6;
  for (int i = tid; i < 4 * HV / 2; i += BLK) whd[i] = 0u;
  __syncthreads();
  int base = t * TILE;
  int end  = min(base + TILE, N);
  int sb = base + wv * SUBT;
  int se = min(sb + SUBT, end);
  const unsigned char* ht = hist + (size_t)t * HV;  // saturated tile-start offsets
  unsigned short lb[NCH], lr[NCH];
  const unsigned long long lmask = (1ULL << lane) - 1ULL;
#pragma unroll
  for (int c = 0; c < NCH; ++c) {
    int i = sb + c * 64 + lane;
    int b = 4095;                                   // sentinel (> any real bin)
    if (i < se) {
      int bi = bins[i];
      if (bi < HV && ht[bi] < 64) b = bi;           // prune dead bins
    }
    lb[c] = (unsigned short)b;
    lr[c] = 0;
    if (__ballot(b != 4095) == 0ULL) continue;      // whole chunk dead
    unsigned long long m = ~0ULL;
#pragma unroll
    for (int k = 0; k < 12; ++k) {
      unsigned long long bal = __ballot((b >> k) & 1);
      m &= ((b >> k) & 1) ? bal : ~bal;
    }
    int rho = __popcll(m & lmask);                  // same-bin lanes before me
    int kap = __popcll(m);                          // same-bin lanes in chunk
    int cv = 0;
    if (b != 4095) {
      cv = wh[wv][b];                               // read before leader write
      if (rho == 0) wh[wv][b] = (unsigned short)(cv + kap);
    }
    lr[c] = (unsigned short)(cv + rho);
  }
  __syncthreads();
  for (int j = tid; j < HV; j += BLK) {
    int a0 = wh[0][j], a1 = wh[1][j], a2 = wh[2][j];
    wh[0][j] = 0;
    wh[1][j] = (unsigned short)a0;
    wh[2][j] = (unsigned short)(a0 + a1);
    wh[3][j] = (unsigned short)(a0 + a1 + a2);
  }
  __syncthreads();
#pragma unroll
  for (int c = 0; c < NCH; ++c) {
    int b = lb[c];
    if (b == 4095) continue;
    int rank = (int)ht[b] + (int)wh[wv][b] + (int)lr[c];
    if (rank < MAXP) {
      int s = soh[b];
      if (s >= 0) {
        int i = sb + c * 64 + lane;
        size_t dst = (size_t)(s * MAXP + rank) * 5;
        size_t src = (size_t)i * 5;
        out[dst + 0] = pts[src + 0];
        out[dst + 1] = pts[src + 1];
        out[dst + 2] = pts[src + 2];
        out[dst + 3] = pts[src + 3];
        out[dst + 4] = pts[src + 4];
      }
    }
  }
}

// ---- pass 3 (generic fallback, any tile) ----
__global__ void k_scatter_gen(const float* __restrict__ pts, int N, int tile,
                              const unsigned char* __restrict__ hist,
                              const unsigned short* __restrict__ bins,
                              const int* __restrict__ soh,
                              float* __restrict__ out) {
  __shared__ int cur[HV + 1];
  int t = blockIdx.x;
  int tid = threadIdx.x;
  const unsigned char* ht = hist + (size_t)t * HV;
  for (int i = tid; i < HV + 1; i += BLK) cur[i] = (i < HV) ? (int)ht[i] : 0;
  __syncthreads();
  int base = t * tile;
  int end  = min(base + tile, N);
  int lane = tid & 63, wv = tid >> 6;
  for (int g = base; g < base + tile; g += BLK) {
    int i = g + tid;
    bool act = (i < end);
    int b = act ? (int)bins[i] : 0x10000;
    int rho = 0, kap = 0;
    for (int j = 0; j < 64; ++j) {
      int bj = __shfl(b, j, 64);
      if (bj == b) { kap++; if (j < lane) rho++; }
    }
    int rank = 0x7FFFFFFF;
    for (int w = 0; w < 4; ++w) {
      if (wv == w && act) {
        int bs = cur[b];
        rank = bs + rho;
        if (rho == 0) cur[b] = bs + kap;
      }
      __syncthreads();
    }
    if (act && rank < MAXP && b < HV) {
      int s = soh[b];
      if (s >= 0) {
        size_t dst = (size_t)(s * MAXP + rank) * 5;
        size_t src = (size_t)i * 5;
        out[dst + 0] = pts[src + 0];
        out[dst + 1] = pts[src + 1];
        out[dst + 2] = pts[src + 2];
        out[dst + 3] = pts[src + 3];
        out[dst + 4] = pts[src + 4];
      }
    }
  }
}

extern "C" void kernel_launch(void* const* d_in, const int* in_sizes, int n_in,
                              void* d_out, int out_size, void* d_ws, size_t ws_size,
                              hipStream_t stream) {
  const float* pts = (const float*)d_in[0];
  int N = in_sizes[0] / 5;
  float* out = (float*)d_out;

  auto align = [](size_t x) { return (x + 255) & ~(size_t)255; };
  int tile = TILE, NT = 1, NC = 1;
  size_t o_hist = 0, o_part = 0, o_soh = 0, o_bins = 0;
  for (;;) {
    NT = (N + tile - 1) / tile;
    NC = (NT + CHT - 1) / CHT;
    o_hist = 0;
    o_part = align(o_hist + (size_t)NT * HV);
    o_soh  = align(o_part + (size_t)NC * HV);
    o_bins = align(o_soh + (size_t)HV * 4);
    size_t need = o_bins + (size_t)N * 2;
    if (need <= ws_size || tile >= (1 << 22)) break;
    tile <<= 1;
  }

  char* w = (char*)d_ws;
  unsigned char* hist = (unsigned char*)(w + o_hist);
  unsigned int*  hist32 = (unsigned int*)hist;
  unsigned int*  part32 = (unsigned int*)(w + o_part);
  int* soh = (int*)(w + o_soh);
  unsigned short* bins = (unsigned short*)(w + o_bins);

  int n4 = out_size / 4;
  int tailN = out_size - n4 * 4;

  k_hist<<<NT, BLK, 0, stream>>>(pts, N, tile, n4, tailN, hist, bins, (float4*)out);
  dim3 ga((HVW + BLK - 1) / BLK, NC);
  k_scan_a<<<ga, BLK, 0, stream>>>(hist32, NT, part32);
  k_bsc<<<1, 1024, 0, stream>>>(part32, NC, soh, out);
  k_scan_c<<<ga, BLK, 0, stream>>>(hist32, NT, part32);
  if (tile == TILE) {
    k_scatter_fast<<<NT, BLK, 0, stream>>>(pts, N, hist, bins, soh, out);
  } else {
    k_scatter_gen<<<NT, BLK, 0, stream>>>(pts, N, tile, hist, bins, soh, out);
  }
}

// Round 8
// 88.205 us; speedup vs baseline: 1.1053x; 1.0596x over previous
//
#include <hip/hip_runtime.h>
#include <math.h>

// ---- problem constants ----
#define NRAD 48
#define NANG 72
#define HV   3456            // valid hashes = NRAD*NANG
#define HVW  864             // HV/4 (u32 words of packed u8 counters)
#define MAXP 64
#define MAXV 3000
#define BLK  256
#define CHT  16              // tiles per scan chunk
#define TILE 4096
#define SUBT 1024            // per-wave sub-tile in fast scatter (TILE/4)
#define NCH  16              // chunks per sub-tile (SUBT/64)

// output layout (floats)
#define OFF_C   (MAXV*MAXP*5)          // 960000
#define OFF_N   (OFF_C + MAXV*3)       // 969000
#define OFF_X   (OFF_N + MAXV)         // 972000

#define PI_F 3.14159265358979323846f   // rounds to 0x40490FDB

// np.linspace(-pi, pi, 73) in f64 (y = i*step + start, endpoint forced), cast f32.
__device__ __forceinline__ float angle_edge(int j) {
  const double PI = 3.14159265358979311599796346854;
  const double step = (PI - (-PI)) / 72.0;
  if (j == 72) return (float)PI;
  return (float)(-PI + (double)j * step);
}

__device__ __forceinline__ float next_up_f(float e) {
  if (e == 0.0f) return __uint_as_float(1u);
  unsigned u = __float_as_uint(e);
  u = (e > 0.0f) ? (u + 1u) : (u - 1u);
  return __uint_as_float(u);
}
__device__ __forceinline__ float next_dn_f(float e) {
  if (e == 0.0f) return -__uint_as_float(1u);
  unsigned u = __float_as_uint(e);
  u = (e > 0.0f) ? (u - 1u) : (u + 1u);
  return __uint_as_float(u);
}

// Angular bin, reference semantics: largest g in [0,71] with eang[g] < theta_f32
// (clip), valid iff theta_f32 < eang[72]. theta_f32 = f32-rounded atan2.
// Fast path: f32 cross tests vs edge directions with guard GA=2e-6*r (covers
// f32 cross rounding ~3e-7*r and the half-ulp boundary offset ~1.2e-7*r).
// Uncertain: f64 cross tests vs the EXACT rounding boundaries UB_j = e_j+h/2
// (theta > UB_j <=> theta_f32 > e_j), B72 = e72-h/2 (theta >= B72 <=> invalid).
// No libm atan2 anywhere -> pure f32 hot loop, low VGPR.
__device__ __forceinline__ int point_bin(float x, float y, float z,
                                         const float* __restrict__ ec,
                                         const float* __restrict__ es,
                                         const double* __restrict__ cB,
                                         const double* __restrict__ sB) {
  float r = __fsqrt_rn(__fadd_rn(__fmul_rn(x, x), __fmul_rn(y, y)));
  if (!(z >= -3.0f && z < 5.0f && r >= 2.0f && r < 50.0f)) return HV;
  int ri = (int)ceilf(r) - 3;                 // exact: edges are ints 2..50
  ri = max(0, min(NRAD - 1, ri));
  // cheap guess (err ~3e-4 rad)
  float ax = fabsf(x), ay = fabsf(y);
  float u = fminf(ax, ay), U = fmaxf(ax, ay);
  bool big = u > 0.41421356f * U;
  float num = big ? (U - u) : u;
  float den = big ? (U + u) : U;
  float v = num * __builtin_amdgcn_rcpf(den);
  float s2 = v * v;
  float pp = v * (1.0f + s2 * (-0.33333333f + s2 * (0.2f - s2 * 0.14285714f)));
  float th1 = big ? (0.78539816f - pp) : pp;
  if (ay > ax) th1 = 1.57079633f - th1;
  if (x < 0.0f) th1 = PI_F - th1;
  float that = copysignf(th1, y);
  int g = (int)floorf((that + PI_F) * 11.459155902616465f);
  g = max(0, min(NANG - 1, g));
  float GA = 2e-6f * r;
  bool unc = false;
  for (;;) {                                   // ensure theta > edge_g (certainly)
    float d = __fmaf_rn(ec[g], y, -__fmul_rn(es[g], x));
    if (d > GA) break;
    if (d > -GA || g == 0) { unc = true; break; }
    --g;
  }
  if (!unc) {
    while (g < NANG - 1) {                     // advance while theta > edge_{g+1}
      float d = __fmaf_rn(ec[g + 1], y, -__fmul_rn(es[g + 1], x));
      if (d < -GA) break;
      if (d <= GA) { unc = true; break; }
      ++g;
    }
    if (!unc && g == NANG - 1) {               // upper validity: theta < eang[72]
      float d = __fmaf_rn(ec[72], y, -__fmul_rn(es[72], x));
      if (d >= -GA) unc = true; else return ri * NANG + g;
    } else if (!unc) {
      return ri * NANG + g;
    }
  }
  // exact f64 boundary walk (rare, ~1e-4 of points)
  double xd = (double)x, yd = (double)y;
  for (;;) {
    if (g == 0) break;
    double d = cB[g] * yd - sB[g] * xd;        // sign(theta - UB_g)
    if (d > 0.0) break;
    --g;
  }
  while (g < NANG - 1) {
    double d = cB[g + 1] * yd - sB[g + 1] * xd;
    if (!(d > 0.0)) break;
    ++g;
  }
  if (g == NANG - 1) {
    double d = cB[72] * yd - sB[72] * xd;      // sign(theta - B72)
    if (d >= 0.0) return HV;                   // theta_f32 >= eang[72]
  }
  return ri * NANG + g;
}

// ---- pass 1: zero d_out + per-tile saturated u8 histogram + bin cache ----
__global__ __launch_bounds__(BLK) void k_hist(
    const float* __restrict__ pts, int N, int tile, int n4, int tailN,
    unsigned char* __restrict__ hist, unsigned short* __restrict__ bins,
    float4* __restrict__ out4) {
  __shared__ int lh[HV];
  __shared__ float ec[73], es[73];
  __shared__ double cB[73], sB[73];
  int t = blockIdx.x, tid = threadIdx.x;
  for (int j = t * BLK + tid; j < n4; j += gridDim.x * BLK)
    out4[j] = make_float4(0.f, 0.f, 0.f, 0.f);
  if (t == 0 && tid < tailN) ((float*)out4)[(size_t)n4 * 4 + tid] = 0.f;
  for (int i = tid; i < HV; i += BLK) lh[i] = 0;
  if (tid < 73) {
    float e = angle_edge(tid);
    double ed = (double)e;
    ec[tid] = (float)cos(ed);
    es[tid] = (float)sin(ed);
    double bnd;
    if (tid < 72) bnd = ed + 0.5 * ((double)next_up_f(e) - ed);   // UB_j
    else          bnd = ed - 0.5 * (ed - (double)next_dn_f(e));   // B72
    cB[tid] = cos(bnd);
    sB[tid] = sin(bnd);
  }
  __syncthreads();
  int base = t * tile;
  int end  = min(base + tile, N);
  int endq = base + (((end - base) >> 2) << 2);
  const float4* p4 = (const float4*)pts;
  for (int i0 = base + (tid << 2); i0 < endq; i0 += (BLK << 2)) {
    size_t q = (size_t)(i0 >> 2) * 5;
    float4 v0 = p4[q], v1 = p4[q + 1], v2 = p4[q + 2], v3 = p4[q + 3], v4 = p4[q + 4];
    int b0 = point_bin(v0.x, v0.y, v0.z, ec, es, cB, sB);
    int b1 = point_bin(v1.y, v1.z, v1.w, ec, es, cB, sB);
    int b2 = point_bin(v2.z, v2.w, v3.x, ec, es, cB, sB);
    int b3 = point_bin(v3.w, v4.x, v4.y, ec, es, cB, sB);
    *(ushort4*)(bins + i0) = make_ushort4((unsigned short)b0, (unsigned short)b1,
                                          (unsigned short)b2, (unsigned short)b3);
    if (b0 < HV) atomicAdd(&lh[b0], 1);
    if (b1 < HV) atomicAdd(&lh[b1], 1);
    if (b2 < HV) atomicAdd(&lh[b2], 1);
    if (b3 < HV) atomicAdd(&lh[b3], 1);
  }
  for (int i = endq + tid; i < end; i += BLK) {   // <=3 tail points
    size_t p = (size_t)i * 5;
    int b = point_bin(pts[p], pts[p + 1], pts[p + 2], ec, es, cB, sB);
    bins[i] = (unsigned short)b;
    if (b < HV) atomicAdd(&lh[b], 1);
  }
  __syncthreads();
  unsigned char* ht = hist + (size_t)t * HV;
  for (int i = tid; i < HV; i += BLK) ht[i] = (unsigned char)min(lh[i], 64);
}

// ---- pass 2a: per-chunk saturated sums (u32-packed u8 lanes) ----
__global__ void k_scan_a(const unsigned int* __restrict__ hist32, int NT,
                         unsigned int* __restrict__ part32) {
  int w = blockIdx.x * BLK + threadIdx.x;     // word 0..HVW-1 (4 bins per word)
  int c = blockIdx.y;
  if (w >= HVW) return;
  int t0 = c * CHT, t1 = min(t0 + CHT, NT);
  int s0 = 0, s1 = 0, s2 = 0, s3 = 0;
  for (int t = t0; t < t1; ++t) {
    unsigned int v = hist32[(size_t)t * HVW + w];
    s0 = min(s0 + (int)(v & 255u), 64);
    s1 = min(s1 + (int)((v >> 8) & 255u), 64);
    s2 = min(s2 + (int)((v >> 16) & 255u), 64);
    s3 = min(s3 + (int)(v >> 24), 64);
  }
  part32[(size_t)c * HVW + w] = (unsigned)s0 | ((unsigned)s1 << 8) |
                                ((unsigned)s2 << 16) | ((unsigned)s3 << 24);
}

// ---- pass 2b (merged): blocks 0..NC-1 apply tile-exclusive scan (own base from
// raw chunk sums, no dependency on a separate scan of part); block NC does slot
// assignment + coords/num_points/centers. part32 is read-only here.
__global__ __launch_bounds__(1024) void k_scan_cb(
    unsigned int* __restrict__ hist32, int NT, int NC,
    const unsigned int* __restrict__ part32,
    int* __restrict__ soh, float* __restrict__ out) {
  int blk = blockIdx.x;
  int tid = threadIdx.x;
  if (blk < NC) {
    if (tid >= HVW) return;
    int r0 = 0, r1 = 0, r2 = 0, r3 = 0;
    for (int cc = 0; cc < blk; ++cc) {
      unsigned int v = part32[(size_t)cc * HVW + tid];
      r0 = min(r0 + (int)(v & 255u), 64);
      r1 = min(r1 + (int)((v >> 8) & 255u), 64);
      r2 = min(r2 + (int)((v >> 16) & 255u), 64);
      r3 = min(r3 + (int)(v >> 24), 64);
    }
    int t0 = blk * CHT, t1 = min(t0 + CHT, NT);
    for (int t = t0; t < t1; ++t) {
      size_t o = (size_t)t * HVW + tid;
      unsigned int v = hist32[o];
      hist32[o] = (unsigned)r0 | ((unsigned)r1 << 8) |
                  ((unsigned)r2 << 16) | ((unsigned)r3 << 24);
      r0 = min(r0 + (int)(v & 255u), 64);
      r1 = min(r1 + (int)((v >> 8) & 255u), 64);
      r2 = min(r2 + (int)((v >> 16) & 255u), 64);
      r3 = min(r3 + (int)(v >> 24), 64);
    }
  } else {
    __shared__ float eang[73];
    __shared__ int ssum[1024];
    if (tid < 73) eang[tid] = angle_edge(tid);
    int c0 = 0, c1 = 0, c2 = 0, c3 = 0;
    if (tid < HVW) {
      for (int cc = 0; cc < NC; ++cc) {
        unsigned int v = part32[(size_t)cc * HVW + tid];
        c0 = min(c0 + (int)(v & 255u), 64);
        c1 = min(c1 + (int)((v >> 8) & 255u), 64);
        c2 = min(c2 + (int)((v >> 16) & 255u), 64);
        c3 = min(c3 + (int)(v >> 24), 64);
      }
    }
    int occ = (c0 > 0) + (c1 > 0) + (c2 > 0) + (c3 > 0);
    ssum[tid] = occ;
    __syncthreads();
    for (int off = 1; off < 1024; off <<= 1) {
      int v = (tid >= off) ? ssum[tid - off] : 0;
      __syncthreads();
      ssum[tid] += v;
      __syncthreads();
    }
    int base = ssum[tid] - occ;               // exclusive slot base (bin order)
    if (tid < HVW) {
      int cs[4] = {c0, c1, c2, c3};
#pragma unroll
      for (int k = 0; k < 4; ++k) {
        int h = tid * 4 + k;
        int cnt = cs[k];
        int s = -1;
        if (cnt > 0) {
          if (base < MAXV) s = base;
          base++;
        }
        soh[h] = s;
        if (s >= 0) {
          int ri = h / NANG, ti = h % NANG;
          out[OFF_C + s * 3 + 0] = (float)ri;
          out[OFF_C + s * 3 + 1] = (float)ti;
          out[OFF_C + s * 3 + 2] = 0.0f;
          out[OFF_N + s] = (float)cnt;        // already saturated at 64
          float rc = 2.5f + (float)ri;
          float tc = 0.5f * (eang[ti] + eang[ti + 1]);
          out[OFF_X + s * 2 + 0] = rc * cosf(tc);   // ~5e-5 abs err << threshold
          out[OFF_X + s * 2 + 1] = rc * sinf(tc);
        }
      }
    }
  }
}

// ---- pass 3 (fast, tile==4096): ballot-rank scatter with dead-bin pruning ----
__global__ __launch_bounds__(BLK) void k_scatter_fast(
    const float* __restrict__ pts, int N,
    const unsigned char* __restrict__ hist, const unsigned short* __restrict__ bins,
    const int* __restrict__ soh, float* __restrict__ out) {
  __shared__ unsigned int whd[4 * HV / 2];          // 4 x HV u16 = 27648 B
  unsigned short (*wh)[HV] = (unsigned short (*)[HV])whd;
  int t = blockIdx.x;
  int tid = threadIdx.x;
  int lane = tid & 63, wv = tid >> 6;
  for (int i = tid; i < 4 * HV / 2; i += BLK) whd[i] = 0u;
  __syncthreads();
  int base = t * TILE;
  int end  = min(base + TILE, N);
  int sb = base + wv * SUBT;
  int se = min(sb + SUBT, end);
  const unsigned char* ht = hist + (size_t)t * HV;  // saturated tile-start offsets
  unsigned short lb[NCH], lr[NCH];
  const unsigned long long lmask = (1ULL << lane) - 1ULL;
#pragma unroll
  for (int c = 0; c < NCH; ++c) {
    int i = sb + c * 64 + lane;
    int b = 4095;                                   // sentinel (> any real bin)
    if (i < se) {
      int bi = bins[i];
      if (bi < HV && ht[bi] < 64) b = bi;           // prune dead bins
    }
    lb[c] = (unsigned short)b;
    lr[c] = 0;
    if (__ballot(b != 4095) == 0ULL) continue;      // whole chunk dead
    unsigned long long m = ~0ULL;
#pragma unroll
    for (int k = 0; k < 12; ++k) {
      unsigned long long bal = __ballot((b >> k) & 1);
      m &= ((b >> k) & 1) ? bal : ~bal;
    }
    int rho = __popcll(m & lmask);                  // same-bin lanes before me
    int kap = __popcll(m);                          // same-bin lanes in chunk
    int cv = 0;
    if (b != 4095) {
      cv = wh[wv][b];                               // read before leader write
      if (rho == 0) wh[wv][b] = (unsigned short)(cv + kap);
    }
    lr[c] = (unsigned short)(cv + rho);
  }
  __syncthreads();
  for (int j = tid; j < HV; j += BLK) {
    int a0 = wh[0][j], a1 = wh[1][j], a2 = wh[2][j];
    wh[0][j] = 0;
    wh[1][j] = (unsigned short)a0;
    wh[2][j] = (unsigned short)(a0 + a1);
    wh[3][j] = (unsigned short)(a0 + a1 + a2);
  }
  __syncthreads();
#pragma unroll
  for (int c = 0; c < NCH; ++c) {
    int b = lb[c];
    if (b == 4095) continue;
    int rank = (int)ht[b] + (int)wh[wv][b] + (int)lr[c];
    if (rank < MAXP) {
      int s = soh[b];
      if (s >= 0) {
        int i = sb + c * 64 + lane;
        size_t dst = (size_t)(s * MAXP + rank) * 5;
        size_t src = (size_t)i * 5;
        out[dst + 0] = pts[src + 0];
        out[dst + 1] = pts[src + 1];
        out[dst + 2] = pts[src + 2];
        out[dst + 3] = pts[src + 3];
        out[dst + 4] = pts[src + 4];
      }
    }
  }
}

// ---- pass 3 (generic fallback, any tile) ----
__global__ void k_scatter_gen(const float* __restrict__ pts, int N, int tile,
                              const unsigned char* __restrict__ hist,
                              const unsigned short* __restrict__ bins,
                              const int* __restrict__ soh,
                              float* __restrict__ out) {
  __shared__ int cur[HV + 1];
  int t = blockIdx.x;
  int tid = threadIdx.x;
  const unsigned char* ht = hist + (size_t)t * HV;
  for (int i = tid; i < HV + 1; i += BLK) cur[i] = (i < HV) ? (int)ht[i] : 0;
  __syncthreads();
  int base = t * tile;
  int end  = min(base + tile, N);
  int lane = tid & 63, wv = tid >> 6;
  for (int g = base; g < base + tile; g += BLK) {
    int i = g + tid;
    bool act = (i < end);
    int b = act ? (int)bins[i] : 0x10000;
    int rho = 0, kap = 0;
    for (int j = 0; j < 64; ++j) {
      int bj = __shfl(b, j, 64);
      if (bj == b) { kap++; if (j < lane) rho++; }
    }
    int rank = 0x7FFFFFFF;
    for (int w = 0; w < 4; ++w) {
      if (wv == w && act) {
        int bs = cur[b];
        rank = bs + rho;
        if (rho == 0) cur[b] = bs + kap;
      }
      __syncthreads();
    }
    if (act && rank < MAXP && b < HV) {
      int s = soh[b];
      if (s >= 0) {
        size_t dst = (size_t)(s * MAXP + rank) * 5;
        size_t src = (size_t)i * 5;
        out[dst + 0] = pts[src + 0];
        out[dst + 1] = pts[src + 1];
        out[dst + 2] = pts[src + 2];
        out[dst + 3] = pts[src + 3];
        out[dst + 4] = pts[src + 4];
      }
    }
  }
}

extern "C" void kernel_launch(void* const* d_in, const int* in_sizes, int n_in,
                              void* d_out, int out_size, void* d_ws, size_t ws_size,
                              hipStream_t stream) {
  const float* pts = (const float*)d_in[0];
  int N = in_sizes[0] / 5;
  float* out = (float*)d_out;

  auto align = [](size_t x) { return (x + 255) & ~(size_t)255; };
  int tile = TILE, NT = 1, NC = 1;
  size_t o_hist = 0, o_part = 0, o_soh = 0, o_bins = 0;
  for (;;) {
    NT = (N + tile - 1) / tile;
    NC = (NT + CHT - 1) / CHT;
    o_hist = 0;
    o_part = align(o_hist + (size_t)NT * HV);
    o_soh  = align(o_part + (size_t)NC * HV);
    o_bins = align(o_soh + (size_t)HV * 4);
    size_t need = o_bins + (size_t)N * 2;
    if (need <= ws_size || tile >= (1 << 22)) break;
    tile <<= 1;
  }

  char* w = (char*)d_ws;
  unsigned char* hist = (unsigned char*)(w + o_hist);
  unsigned int*  hist32 = (unsigned int*)hist;
  unsigned int*  part32 = (unsigned int*)(w + o_part);
  int* soh = (int*)(w + o_soh);
  unsigned short* bins = (unsigned short*)(w + o_bins);

  int n4 = out_size / 4;
  int tailN = out_size - n4 * 4;

  k_hist<<<NT, BLK, 0, stream>>>(pts, N, tile, n4, tailN, hist, bins, (float4*)out);
  dim3 ga((HVW + BLK - 1) / BLK, NC);
  k_scan_a<<<ga, BLK, 0, stream>>>(hist32, NT, part32);
  k_scan_cb<<<NC + 1, 1024, 0, stream>>>(hist32, NT, NC, part32, soh, out);
  if (tile == TILE) {
    k_scatter_fast<<<NT, BLK, 0, stream>>>(pts, N, hist, bins, soh, out);
  } else {
    k_scatter_gen<<<NT, BLK, 0, stream>>>(pts, N, tile, hist, bins, soh, out);
  }
}